// Round 5
// baseline (55.410 us; speedup 1.0000x reference)
//
#include <hip/hip_runtime.h>
#include <math.h>
#include <stdint.h>

static constexpr int B = 32, H = 256, N = 512, T = 2048;
static constexpr int TTILE = 128;  // t-tile per fused block
static constexpr int KC = 64;      // n-chunk
static constexpr int NCHUNK = N / KC;   // 8
static constexpr float kLOG_2PI = 1.8378770664093453f;
static constexpr float kLOG2E   = 1.4426950408889634f;
static constexpr float kNEG_BIG = -3.0e38f;
static constexpr float kRANGE_DELTA = 26.0f;  // log2 threshold below max

typedef __attribute__((ext_vector_type(8))) short bf16x8;
typedef __attribute__((ext_vector_type(4))) float f32x4;

static __device__ __forceinline__ short f2bf(float f) {
  unsigned u = __float_as_uint(f);
  unsigned r = (u + 0x7fffu + ((u >> 16) & 1u)) >> 16;   // RNE
  return (short)r;
}

static __device__ __forceinline__ void gload_lds16(const void* g, void* l) {
  __builtin_amdgcn_global_load_lds(
      (const __attribute__((address_space(1))) unsigned int*)g,
      (__attribute__((address_space(3))) unsigned int*)l, 16, 0, 0);
}

// Kernel 1: per-batch centers c[n]=cumsum(d)-0.5d, base-2 coeffs, and per-b
// window stats: bstat[b] = {W (search half-width), t_far (window-valid limit)}.
__global__ void k_prep(const float* __restrict__ dur, const float* __restrict__ vars,
                       const int* __restrict__ lens,
                       float* __restrict__ c, float* __restrict__ a2, float* __restrict__ q2,
                       float2* __restrict__ bstat) {
  const int b = blockIdx.x;
  const int lane = threadIdx.x;  // 64
  const int L = lens[b];
  float running = 0.f;
  float a2max = kNEG_BIG, a2min = -kNEG_BIG, q2min = -kNEG_BIG, q2max = kNEG_BIG;
  float dmax = 0.f, clast = 0.f;
  for (int i = 0; i < N / 64; ++i) {
    const int n = i * 64 + lane;
    const float d = dur[b * N + n];
    float x = d;
#pragma unroll
    for (int off = 1; off < 64; off <<= 1) {
      float up = __shfl_up(x, off, 64);
      if (lane >= off) x += up;
    }
    const float cc = running + x - 0.5f * d;
    running += __shfl(x, 63, 64);
    const float v = vars[b * N + n];
    const float a2v = -0.5f * (kLOG_2PI + logf(v)) * kLOG2E;
    const float q2v = 0.5f * kLOG2E / v;
    c[b * N + n]  = cc;
    a2[b * N + n] = a2v;
    q2[b * N + n] = q2v;
    if (n < L) {
      a2max = fmaxf(a2max, a2v); a2min = fminf(a2min, a2v);
      q2min = fminf(q2min, q2v); q2max = fmaxf(q2max, q2v);
      dmax = fmaxf(dmax, d);
      if (n == L - 1) clast = cc;
    }
  }
#pragma unroll
  for (int off = 32; off; off >>= 1) {
    a2max = fmaxf(a2max, __shfl_xor(a2max, off, 64));
    a2min = fminf(a2min, __shfl_xor(a2min, off, 64));
    q2min = fminf(q2min, __shfl_xor(q2min, off, 64));
    q2max = fmaxf(q2max, __shfl_xor(q2max, off, 64));
    dmax  = fmaxf(dmax,  __shfl_xor(dmax,  off, 64));
    clast = fmaxf(clast, __shfl_xor(clast, off, 64));
  }
  if (lane == 0) {
    const float dnb = 0.5f * dmax;                    // max dist to nearest center
    const float m_lower = a2min - q2max * dnb * dnb;  // m(t) >= this for covered t
    const float R = sqrtf((a2max - m_lower + kRANGE_DELTA + 1.0f) / q2min);
    bstat[b] = make_float2(R + 1.0f, clast + dnb);
  }
}

// Kernel 2: enc fp32 -> bf16 pre-swizzled 32KB chunk images for global_load_lds.
__global__ __launch_bounds__(256) void k_enc_cvt(const float* __restrict__ enc,
                                                 const int* __restrict__ lens,
                                                 short* __restrict__ encbf) {
  const int cc = blockIdx.x;
  const int b = blockIdx.y;
  if (cc * KC >= lens[b]) return;
  const int tid = threadIdx.x;
  const float* encb = enc + (size_t)b * H * N + cc * KC;
  char* img = (char*)encbf + ((size_t)(b * NCHUNK + cc)) * (H * KC * 2);
#pragma unroll
  for (int i = 0; i < 8; ++i) {
    const int flat = i * 256 + tid;        // h*8 + j8
    const int h = flat >> 3, j8 = flat & 7;
    const float4 v0 = *(const float4*)(encb + h * N + j8 * 8);
    const float4 v1 = *(const float4*)(encb + h * N + j8 * 8 + 4);
    bf16x8 w;
    w[0] = f2bf(v0.x); w[1] = f2bf(v0.y); w[2] = f2bf(v0.z); w[3] = f2bf(v0.w);
    w[4] = f2bf(v1.x); w[5] = f2bf(v1.y); w[6] = f2bf(v1.z); w[7] = f2bf(v1.w);
    const int byte = ((h * KC + j8 * 8) * 2) ^ ((h & 7) << 4);
    *(bf16x8*)(img + byte) = w;
  }
}

// Kernel 3 (fused): per-(b, 128t) block, 512 threads (8 waves).
// Phase 1: window-restricted exact max m(t) + contributing range; far tiles
//          (t beyond last center) use window=[0,L) (exact full scan).
// Phase 2: chunk loop: DMA A image, gen unnormalized p bf16 + s[t], MFMA.
__global__ __launch_bounds__(512, 4) void k_fused(
    const short* __restrict__ encbf, const float* __restrict__ c,
    const float* __restrict__ a2, const float* __restrict__ q2,
    const int* __restrict__ lens, const float2* __restrict__ bstat,
    float* __restrict__ out) {
  __shared__ short eA[H * KC];        // 32 KB swizzled [h][k] (DMA image)
  __shared__ short pB[TTILE * KC];    // 16 KB swizzled [t][k]
  __shared__ float4 ps[N];            // 8 KB: {c, a2, q2, 0}
  __shared__ float m_lds[TTILE];
  __shared__ float s_lds[TTILE];
  __shared__ int sh_i[4];             // nlo, nhi (range union), cntLo, cntHi

  const int b = blockIdx.y;
  const int t0 = blockIdx.x * TTILE;
  const int tid = threadIdx.x;
  const int lane = tid & 63;
  const int wave = tid >> 6;
  const int L = lens[b];
  const float2 bs = bstat[b];

  for (int i = tid; i < N; i += 512)
    ps[i] = make_float4(c[b * N + i], a2[b * N + i], q2[b * N + i], 0.f);
  if (tid < TTILE) s_lds[tid] = 0.f;
  if (tid < 4) sh_i[tid] = (tid == 0) ? N : (tid == 1 ? -1 : 0);
  __syncthreads();

  // ---- window bounds ----
  const bool tile_far = ((float)(t0 + TTILE - 1) > bs.y);
  int n_lo = 0, n_hi = L;
  if (!tile_far) {
    const float loLim = (float)t0 - bs.x;
    const float hiLim = (float)(t0 + TTILE - 1) + bs.x;
    const int n = tid;  // 512 threads cover N
    const bool valid = (n < L);
    const float cv = ps[n].x;
    const unsigned long long mLo = __ballot(valid && (cv < loLim));
    const unsigned long long mHi = __ballot(valid && (cv <= hiLim));
    if (lane == 0) {
      atomicAdd(&sh_i[2], __popcll(mLo));
      atomicAdd(&sh_i[3], __popcll(mHi));
    }
    __syncthreads();
    n_lo = sh_i[2]; n_hi = sh_i[3];
    if (n_hi <= n_lo) { n_lo = 0; n_hi = L; }   // paranoia fallback
  }

  // ---- Phase 1: exact max over window (4 threads per t) ----
  const int tl = tid >> 2, j = tid & 3;
  const float tf = (float)(t0 + tl);
  float m = kNEG_BIG;
  for (int nn = n_lo + j; nn < n_hi; nn += 4) {
    const float4 p4 = ps[nn];
    const float tc = tf - p4.x;
    m = fmaxf(m, fmaf(-p4.z, tc * tc, p4.y));
  }
  m = fmaxf(m, __shfl_xor(m, 1, 64));
  m = fmaxf(m, __shfl_xor(m, 2, 64));
  if (j == 0) m_lds[tl] = m;
  // range pass: block-level union of {n : w2 >= m(t) - 26}
  const float thr = m - kRANGE_DELTA;
  int lo = N, hi = -1;
  for (int nn = n_lo + j; nn < n_hi; nn += 4) {
    const float4 p4 = ps[nn];
    const float tc = tf - p4.x;
    const float ww = fmaf(-p4.z, tc * tc, p4.y);
    if (ww >= thr) { lo = min(lo, nn); hi = max(hi, nn); }
  }
#pragma unroll
  for (int off = 32; off; off >>= 1) {
    lo = min(lo, __shfl_xor(lo, off, 64));
    hi = max(hi, __shfl_xor(hi, off, 64));
  }
  if (lane == 0) { atomicMin(&sh_i[0], lo); atomicMax(&sh_i[1], hi); }
  __syncthreads();

  int nlo = sh_i[0], nhi = sh_i[1];
  nlo = max(0, min(nlo, L - 1)); nhi = max(nlo, min(nhi, L - 1));
  const int c0 = nlo >> 6, c1 = nhi >> 6;

  f32x4 acc[4][4];
#pragma unroll
  for (int mf = 0; mf < 4; ++mf)
#pragma unroll
    for (int tt = 0; tt < 4; ++tt) acc[mf][tt] = (f32x4){0.f, 0.f, 0.f, 0.f};

  const int l15 = lane & 15;
  const int lhi = lane >> 4;
  const int wave_h = wave & 3;   // 4 h-slices of 64
  const int wave_t = wave >> 2;  // 2 t-slices of 64

  // ---- Phase 2: chunk loop ----
  for (int cc = c0; cc <= c1; ++cc) {
    const int n0 = cc * KC;
    __syncthreads();   // prev chunk's MFMA reads done
    // stage A via async DMA: 32 KB = 32 segs of 1 KB, 4 issues/thread
    const char* srcbase = (const char*)encbf + ((size_t)(b * NCHUNK + cc)) * (H * KC * 2);
#pragma unroll
    for (int i = 0; i < 4; ++i) {
      const int seg = i * 8 + wave;  // wave-uniform
      gload_lds16(srcbase + seg * 1024 + lane * 16, (char*)eA + seg * 1024);
    }
    // stage B: unnormalized p[t][k] bf16 + s[t]; XOR'd jj order (bank spread)
#pragma unroll
    for (int i = 0; i < 2; ++i) {
      const int flat = i * 512 + tid;       // t*8 + j8
      const int t = flat >> 3, j8 = flat & 7;
      const int nbase = n0 + j8 * 8;
      const int byte = ((t * KC + j8 * 8) * 2) ^ ((t & 7) << 4);
      bf16x8 w;
      float psum = 0.f;
      if (nbase + 7 < nlo || nbase > nhi) {
        w = (bf16x8){0, 0, 0, 0, 0, 0, 0, 0};
      } else {
        const float mt = m_lds[t];
        const float tft = (float)(t0 + t);
#pragma unroll
        for (int s = 0; s < 8; ++s) {
          const int jx = s ^ j8;
          const int n = nbase + jx;
          const float4 p4 = ps[n];
          const float tc = tft - p4.x;
          const float w2v = fmaf(-p4.z, tc * tc, p4.y);
          const float pv = (n < L) ? exp2f(w2v - mt) : 0.f;
          psum += pv;
          w[jx] = f2bf(pv);
        }
      }
      *(bf16x8*)((char*)pB + byte) = w;
      psum += __shfl_xor(psum, 1, 64);
      psum += __shfl_xor(psum, 2, 64);
      psum += __shfl_xor(psum, 4, 64);
      if ((tid & 7) == 0) atomicAdd(&s_lds[t], psum);
    }
    __syncthreads();  // drains DMA (vmcnt) + LDS writes
    // MFMA: 2 k-steps of 32, skip steps fully outside range
#pragma unroll
    for (int kk = 0; kk < KC; kk += 32) {
      if (n0 + kk > nhi || n0 + kk + 31 < nlo) continue;
      bf16x8 aF[4], bF[4];
#pragma unroll
      for (int mf = 0; mf < 4; ++mf) {
        const int h = wave_h * 64 + mf * 16 + l15;
        const int byte = ((h * KC + kk + lhi * 8) * 2) ^ ((h & 7) << 4);
        aF[mf] = *(const bf16x8*)((const char*)eA + byte);
      }
#pragma unroll
      for (int tt = 0; tt < 4; ++tt) {
        const int t = wave_t * 64 + tt * 16 + l15;
        const int byte = ((t * KC + kk + lhi * 8) * 2) ^ ((t & 7) << 4);
        bF[tt] = *(const bf16x8*)((const char*)pB + byte);
      }
#pragma unroll
      for (int mf = 0; mf < 4; ++mf)
#pragma unroll
        for (int tt = 0; tt < 4; ++tt)
          acc[mf][tt] = __builtin_amdgcn_mfma_f32_16x16x32_bf16(aF[mf], bF[tt], acc[mf][tt], 0, 0, 0);
    }
  }

  // ---- Epilogue: scale by 1/s[t]; C/D: col(t)=lane&15, row(h)=(lane>>4)*4+r
#pragma unroll
  for (int tt = 0; tt < 4; ++tt) {
    const int t = wave_t * 64 + tt * 16 + l15;
    const float is = 1.0f / s_lds[t];
#pragma unroll
    for (int mf = 0; mf < 4; ++mf) {
      const int h = wave_h * 64 + mf * 16 + lhi * 4;
#pragma unroll
      for (int r = 0; r < 4; ++r) {
        out[((size_t)(b * H + h + r)) * T + t0 + t] = acc[mf][tt][r] * is;
      }
    }
  }
}

extern "C" void kernel_launch(void* const* d_in, const int* in_sizes, int n_in,
                              void* d_out, int out_size, void* d_ws, size_t ws_size,
                              hipStream_t stream) {
  const float* enc  = (const float*)d_in[0];
  const float* dur  = (const float*)d_in[1];
  const float* vars = (const float*)d_in[2];
  const int*   lens = (const int*)d_in[3];
  float* out = (float*)d_out;

  char* ws = (char*)d_ws;
  float*  cbuf  = (float*)ws;                // B*N
  float*  a2buf = cbuf + B * N;              // B*N
  float*  q2buf = a2buf + B * N;             // B*N
  float2* bstat = (float2*)(q2buf + B * N);  // B
  short*  encbf = (short*)(bstat + B);       // B*H*N bf16 (8.4 MB), 16B-aligned

  k_prep<<<B, 64, 0, stream>>>(dur, vars, lens, cbuf, a2buf, q2buf, bstat);
  k_enc_cvt<<<dim3(NCHUNK, B), 256, 0, stream>>>(enc, lens, encbf);
  k_fused<<<dim3(T / TTILE, B), 512, 0, stream>>>(encbf, cbuf, a2buf, q2buf, lens, bstat, out);
}